// Round 4
// baseline (2797.307 us; speedup 1.0000x reference)
//
#include <hip/hip_runtime.h>
#include <stdint.h>

// Problem constants
#define VOCAB  50000
#define EMBD   256
#define HIDD   512
#define G4     2048   // 4*HID
#define NBAT   256
#define TSEQ   512

// ---- workspace layout (bytes) ----
#define O_P2    0ull            // P2[v][j*4+g] bf16 : VOCAB*G4*2      = 204,800,000
#define O_EMBT  204800000ull    // emb bf16 [V][E] (dead after k_proj; tagged hbuf lives here)
#define O_WIH   230400000ull    // W_ih bf16 [G4][E]
#define O_WHH   231448576ull    // W_hh bf16 [G4][H]
#define O_TOKT  233545728ull    // tokT int [2][T][N]
#define O_HBUF  234594304ull    // (legacy, unused)
#define WS_NEED 235643136ull
#define O_HB2   O_EMBT          // tagged h packets [2 lstm][2 phase][256 rows][256 pk x 8B] = 2 MiB

typedef __bf16 bf16x8 __attribute__((ext_vector_type(8)));
typedef float  f32x4  __attribute__((ext_vector_type(4)));
typedef float  f32x16 __attribute__((ext_vector_type(16)));
typedef unsigned long long u64;

__device__ __forceinline__ unsigned short f2bf(float x) {
  unsigned u = __float_as_uint(x);
  u = (u + 0x7fffu + ((u >> 16) & 1u)) >> 16;   // RNE
  return (unsigned short)u;
}
__device__ __forceinline__ float b2f(unsigned short b) {
  return __uint_as_float(((unsigned)b) << 16);
}
__device__ __forceinline__ float sigf(float x) {
  float e = __builtin_amdgcn_exp2f(-1.4426950408889634f * x);
  return __builtin_amdgcn_rcpf(1.0f + e);
}
__device__ __forceinline__ float tanhf_(float x) {
  float e = __builtin_amdgcn_exp2f(-2.8853900817779268f * x);
  return 2.0f * __builtin_amdgcn_rcpf(1.0f + e) - 1.0f;
}

// ------------------------------------------------------------------
// K1: prep — bf16 converts, token transpose
// ------------------------------------------------------------------
__global__ void k_prep(const float* __restrict__ emb, const float* __restrict__ wih,
                       const float* __restrict__ whh, const int* __restrict__ tok1,
                       const int* __restrict__ tok2, unsigned short* __restrict__ embT,
                       unsigned short* __restrict__ wihb, unsigned short* __restrict__ whhb,
                       int* __restrict__ tokT)
{
  const int stride = gridDim.x * blockDim.x;
  const int id0 = blockIdx.x * blockDim.x + threadIdx.x;
  for (int i = id0; i < VOCAB * EMBD; i += stride) embT[i] = f2bf(emb[i]);
  for (int i = id0; i < G4 * EMBD; i += stride)    wihb[i] = f2bf(wih[i]);
  for (int i = id0; i < G4 * HIDD; i += stride)    whhb[i] = f2bf(whh[i]);
  for (int i = id0; i < 2 * TSEQ * NBAT; i += stride) {
    int l = i >> 17, t = (i >> 8) & 511, n = i & 255;
    tokT[i] = (l ? tok2 : tok1)[n * TSEQ + t];
  }
}

// ------------------------------------------------------------------
// K1b: zero tagged h buffer (2 MiB; runs after k_proj — overlaps embT)
// zeroed packets carry tag=0 == poll target at t=0: no startup special case.
// ------------------------------------------------------------------
__global__ void k_zero(u64* __restrict__ hb)
{
  const int stride = gridDim.x * blockDim.x;
  for (int i = blockIdx.x * blockDim.x + threadIdx.x; i < 262144; i += stride)
    hb[i] = 0ull;
}

// ------------------------------------------------------------------
// K2: vocab projection  P2[v][j*4+g] = emb[v]·W_ih[g*512+j] + b_ih + b_hh
// (unchanged — correctness-verified)
// ------------------------------------------------------------------
__global__ __launch_bounds__(256) void
k_proj(const unsigned short* __restrict__ embT, const unsigned short* __restrict__ wihb,
       const float* __restrict__ bih, const float* __restrict__ bhh,
       unsigned short* __restrict__ P2)
{
  const int l  = threadIdx.x & 63;
  const int w  = threadIdx.x >> 6;
  const int n0 = blockIdx.x * 128 + (w & 1) * 64;
  const int m0 = blockIdx.y * 128 + (w >> 1) * 64;
  const int lq = l >> 4, lc = l & 15;

  f32x4 acc[4][4];
  #pragma unroll
  for (int a = 0; a < 4; ++a)
    #pragma unroll
    for (int b = 0; b < 4; ++b) acc[a][b] = (f32x4){0.f, 0.f, 0.f, 0.f};

  const uint8_t* eb = (const uint8_t*)embT;
  const uint8_t* wb = (const uint8_t*)wihb;
  #pragma unroll
  for (int ks = 0; ks < 8; ++ks) {
    const int koff = ks * 64 + lq * 16;
    bf16x8 a[4], b[4];
    #pragma unroll
    for (int mt = 0; mt < 4; ++mt) {
      int row = m0 + mt * 16 + lc; if (row >= VOCAB) row = VOCAB - 1;
      a[mt] = *(const bf16x8*)(eb + (size_t)row * 512 + koff);
    }
    #pragma unroll
    for (int nt = 0; nt < 4; ++nt) {
      int g = n0 + nt * 16 + lc;
      b[nt] = *(const bf16x8*)(wb + (size_t)g * 512 + koff);
    }
    #pragma unroll
    for (int mt = 0; mt < 4; ++mt)
      #pragma unroll
      for (int nt = 0; nt < 4; ++nt)
        acc[mt][nt] = __builtin_amdgcn_mfma_f32_16x16x32_bf16(a[mt], b[nt], acc[mt][nt], 0, 0, 0);
  }

  #pragma unroll
  for (int mt = 0; mt < 4; ++mt)
    #pragma unroll
    for (int r = 0; r < 4; ++r) {
      const int vrow = m0 + mt * 16 + lq * 4 + r;
      if (vrow < VOCAB) {
        #pragma unroll
        for (int nt = 0; nt < 4; ++nt) {
          const int gcol = n0 + nt * 16 + lc;
          float v = acc[mt][nt][r] + bih[gcol] + bhh[gcol];
          const int colp = ((gcol & 511) << 2) | (gcol >> 9);  // [j][g] permuted
          P2[(size_t)vrow * 2048 + colp] = f2bf(v);
        }
      }
    }
}

// ------------------------------------------------------------------
// K3: persistent LSTM scan. 256 blocks x 256 threads (4 waves).
// block = (lstm, mg: 32 batch rows, jb: 32 hidden cols). wave = gate.
// W_hh B-fragments in VGPRs (proven round 3).
// This round: SELF-TAGGED h packets. packet(8B, atomic) = [h0|h1|tag32].
// - writer: epilogue -> two 8B relaxed agent stores. NO drain, NO flag,
//   NO end-of-step barrier (tag rides with data in one atomic store).
// - reader: polls its own 32 packets until all tags==t; the poll load
//   IS the data load (removes drain + flag leg + separate h-load leg).
// Ordering proof: tag t visible => same-store h is step-t data;
// my poll success at t => every peer stored tag t => (data dep) every
// peer finished its step-(t-1) reads => ping-pong overwrite safe.
// Barriers/step: 2. B2 fences LDS-A write->GEMM read; B3 fences
// gb write->epilogue read; B2/B3 of the NEXT step fence region reuse
// (all waves must arrive before any proceeds).
// LDS declared 160KB to FORCE 1 block/CU (co-residency must not
// depend on the packer).
// ------------------------------------------------------------------
#define GB 32768    // LDS offset of f32 gate buffer (A-tile occupies [0,32768))

__global__ __launch_bounds__(256, 1) void
k_lstm(const uint8_t* __restrict__ P2, const int* __restrict__ tokT,
       const uint8_t* __restrict__ whh, uint8_t* __restrict__ hb2)
{
  __shared__ __align__(16) uint8_t smem[163840];   // oversized on purpose: 1 block/CU
  const int tid  = threadIdx.x;
  const int l    = tid & 63;
  const int w    = tid >> 6;        // wave = gate index
  const int bid  = blockIdx.x;
  const int jb   = bid & 15;
  const int mg   = (bid >> 4) & 7;
  const int lstm = bid >> 7;
  const int m0   = mg * 32;
  const int j0   = jb * 32;

  const size_t pslot = 524288;      // per (lstm,phase): 256 rows x 2KB
  const int em   = tid >> 3;        // epilogue batch row 0..31
  const int ecol = tid & 7;         // epilogue col group (4 cols)
  const int an   = l & 31;          // MFMA A-row / B-col (lane&31)
  const int ah   = l >> 5;          // k-half (lane>>5)

  // ---- load this lane's invariant W_hh B-fragments into registers ----
  bf16x8 wreg[32];
  {
    const uint8_t* wrow = whh + (size_t)(w * 512 + j0 + an) * 1024 + (size_t)ah * 16;
    #pragma unroll
    for (int ks = 0; ks < 32; ++ks)
      wreg[ks] = *(const bf16x8*)(wrow + ks * 32);
  }

  float cst[4] = {0.f, 0.f, 0.f, 0.f};
  int tok_next = tokT[(lstm * TSEQ + 0) * NBAT + m0 + em];

  for (int t = 0; t < TSEQ; ++t) {
    const int tok_cur = tok_next;

    // ---- issue xg gather + next-token load FIRST (hides under the poll) ----
    const uint8_t* xsrc = P2 + (size_t)tok_cur * 4096 + (size_t)j0 * 8 + (size_t)ecol * 32;
    const uint4 xq0 = *(const uint4*)(xsrc);
    const uint4 xq1 = *(const uint4*)(xsrc + 16);
    if (t + 1 < TSEQ) tok_next = tokT[(lstm * TSEQ + (t + 1)) * NBAT + m0 + em];

    // ---- poll own 32 tagged packets (rows m0+2i+(tid>>7), cols (tid&127)*4..+3) ----
    u64 pk[32];
    {
      const uint8_t* hb = hb2 + (size_t)(lstm * 2 + (t & 1)) * pslot
                        + (size_t)(m0 + (tid >> 7)) * 2048 + (size_t)(tid & 127) * 16;
      const unsigned tgt = (unsigned)t;
      int guard = 0;
      for (;;) {
        #pragma unroll
        for (int i = 0; i < 16; ++i) {
          pk[2 * i]     = __hip_atomic_load((const u64*)(hb + (size_t)i * 4096),
                                            __ATOMIC_RELAXED, __HIP_MEMORY_SCOPE_AGENT);
          pk[2 * i + 1] = __hip_atomic_load((const u64*)(hb + (size_t)i * 4096 + 8),
                                            __ATOMIC_RELAXED, __HIP_MEMORY_SCOPE_AGENT);
        }
        unsigned bad = 0;
        #pragma unroll
        for (int i = 0; i < 32; ++i) bad |= ((unsigned)(pk[i] >> 32)) ^ tgt;
        if (bad == 0) break;
        __builtin_amdgcn_s_sleep(1);
        if (++guard > 200000) break;   // fail visible (wrong result), not hung
      }
      // stage into LDS A-tile, xor-swizzled (same layout as round 3)
      const int half = tid & 1;
      const int c    = (tid >> 1) & 63;
      #pragma unroll
      for (int i = 0; i < 16; ++i) {
        const int m = i * 2 + (tid >> 7);
        const u64 v = (pk[2 * i] & 0xffffffffull) | ((pk[2 * i + 1] & 0xffffffffull) << 32);
        *(u64*)(smem + (size_t)m * 1024 + ((c ^ (m & 7)) * 16) + half * 8) = v;
      }
    }
    __syncthreads();   // B2: h LDS ready (also fences A-region reuse across steps)

    // ---- GEMM: gate_w[32x32] = h[32x512] . W_g[32x512]^T (32x32x16 MFMA) ----
    f32x16 acc0{}, acc1{};
    #pragma unroll
    for (int ks = 0; ks < 32; ++ks) {
      const int ch = ks * 2 + ah;
      const bf16x8 av = *(const bf16x8*)(smem + (size_t)an * 1024 + ((ch ^ (an & 7)) * 16));
      if (ks & 1) acc1 = __builtin_amdgcn_mfma_f32_32x32x16_bf16(av, wreg[ks], acc1, 0, 0, 0);
      else        acc0 = __builtin_amdgcn_mfma_f32_32x32x16_bf16(av, wreg[ks], acc0, 0, 0, 0);
    }

    {
      float* gb = (float*)(smem + GB);   // gbuf[g][row 0..31][col 0..31] f32
      #pragma unroll
      for (int r = 0; r < 16; ++r) {
        const int row = (r & 3) + 8 * (r >> 2) + 4 * ah;   // 32x32 C/D mapping
        gb[w * 1024 + row * 32 + an] = acc0[r] + acc1[r];
      }
    }
    __syncthreads();   // B3: gate buffer ready (also fences gb reuse across steps)

    // ---- epilogue: 4 cells/lane, nonlinearity, tagged h packets -> MALL ----
    {
      const float* gb = (const float*)(smem + GB);
      const f32x4 pi = *(const f32x4*)(gb + 0 * 1024 + em * 32 + ecol * 4);
      const f32x4 pf = *(const f32x4*)(gb + 1 * 1024 + em * 32 + ecol * 4);
      const f32x4 pg = *(const f32x4*)(gb + 2 * 1024 + em * 32 + ecol * 4);
      const f32x4 po = *(const f32x4*)(gb + 3 * 1024 + em * 32 + ecol * 4);
      unsigned short xsv[16];
      *(uint4*)(xsv) = xq0;
      *(uint4*)(xsv + 8) = xq1;
      unsigned short hv[4];
      #pragma unroll
      for (int k = 0; k < 4; ++k) {
        const float iv = sigf(pi[k] + b2f(xsv[k * 4 + 0]));
        const float fv = sigf(pf[k] + b2f(xsv[k * 4 + 1]));
        const float gv = tanhf_(pg[k] + b2f(xsv[k * 4 + 2]));
        const float ov = sigf(po[k] + b2f(xsv[k * 4 + 3]));
        const float cv = fv * cst[k] + iv * gv;
        cst[k] = cv;
        hv[k] = f2bf(ov * tanhf_(cv));
      }
      const u64 tagw = ((u64)(unsigned)(t + 1)) << 32;
      const u64 p0 = (u64)hv[0] | ((u64)hv[1] << 16) | tagw;
      const u64 p1 = (u64)hv[2] | ((u64)hv[3] << 16) | tagw;
      uint8_t* hdst = hb2 + (size_t)(lstm * 2 + ((t + 1) & 1)) * pslot
                    + (size_t)(m0 + em) * 2048 + (size_t)(j0 + ecol * 4) * 4;
      __hip_atomic_store((u64*)hdst, p0, __ATOMIC_RELAXED, __HIP_MEMORY_SCOPE_AGENT);
      __hip_atomic_store((u64*)(hdst + 8), p1, __ATOMIC_RELAXED, __HIP_MEMORY_SCOPE_AGENT);
    }
    // no drain, no flag, no barrier: tag rides with data; B2/B3 of the
    // next iteration fence all intra-block LDS reuse.
  }
}

// ------------------------------------------------------------------
// K4: h1*h2 -> logits -> softmax. one wave per batch row.
// Reads the tagged packet layout (final h = phase 0, tag 512; tags ignored).
// ------------------------------------------------------------------
__global__ __launch_bounds__(64) void
k_fc(const uint8_t* __restrict__ hb2, const float* __restrict__ wfc,
     const float* __restrict__ bfc, float* __restrict__ out)
{
  const int n = blockIdx.x, l = threadIdx.x;
  const u64* h1 = (const u64*)(hb2 + (size_t)n * 2048);                  // lstm0 phase0
  const u64* h2 = (const u64*)(hb2 + 2 * 524288ull + (size_t)n * 2048);  // lstm1 phase0
  float s0 = 0.f, s1 = 0.f;
  for (int p = l; p < 256; p += 64) {
    const u64 k1 = h1[p], k2 = h2[p];
    const float a0 = b2f((unsigned short)k1) * b2f((unsigned short)k2);
    const float a1 = b2f((unsigned short)(k1 >> 16)) * b2f((unsigned short)(k2 >> 16));
    s0 += a0 * wfc[2 * p]     + a1 * wfc[2 * p + 1];
    s1 += a0 * wfc[HIDD + 2 * p] + a1 * wfc[HIDD + 2 * p + 1];
  }
  #pragma unroll
  for (int off = 32; off > 0; off >>= 1) {
    s0 += __shfl_down(s0, off, 64);
    s1 += __shfl_down(s1, off, 64);
  }
  if (l == 0) {
    s0 += bfc[0]; s1 += bfc[1];
    float m  = fmaxf(s0, s1);
    float e0 = __builtin_amdgcn_exp2f((s0 - m) * 1.4426950408889634f);
    float e1 = __builtin_amdgcn_exp2f((s1 - m) * 1.4426950408889634f);
    float inv = 1.0f / (e0 + e1);
    out[n * 2 + 0] = e0 * inv;
    out[n * 2 + 1] = e1 * inv;
  }
}

// ------------------------------------------------------------------
extern "C" void kernel_launch(void* const* d_in, const int* in_sizes, int n_in,
                              void* d_out, int out_size, void* d_ws, size_t ws_size,
                              hipStream_t stream) {
  (void)in_sizes; (void)n_in; (void)out_size;
  if (ws_size < WS_NEED) return;   // fail visibly rather than scribble OOB

  const int*   tok1 = (const int*)d_in[0];
  const int*   tok2 = (const int*)d_in[1];
  const float* emb  = (const float*)d_in[2];
  const float* wih  = (const float*)d_in[3];
  const float* whh  = (const float*)d_in[4];
  const float* bih  = (const float*)d_in[5];
  const float* bhh  = (const float*)d_in[6];
  const float* wfc  = (const float*)d_in[7];
  const float* bfc  = (const float*)d_in[8];
  float* out = (float*)d_out;

  uint8_t* ws = (uint8_t*)d_ws;
  unsigned short* P2    = (unsigned short*)(ws + O_P2);
  unsigned short* embT  = (unsigned short*)(ws + O_EMBT);
  unsigned short* wihb  = (unsigned short*)(ws + O_WIH);
  unsigned short* whhb  = (unsigned short*)(ws + O_WHH);
  int*            tokT  = (int*)(ws + O_TOKT);
  uint8_t*        hb2   = ws + O_HB2;   // overlaps embT (dead after k_proj)

  k_prep<<<1024, 256, 0, stream>>>(emb, wih, whh, tok1, tok2, embT, wihb, whhb, tokT);
  k_proj<<<dim3(16, 391), 256, 0, stream>>>(embT, wihb, bih, bhh, P2);
  k_zero<<<1024, 256, 0, stream>>>((u64*)hb2);   // embT dead after k_proj

  {
    const uint8_t* p2p = (const uint8_t*)P2;
    const int*     tkp = tokT;
    const uint8_t* whp = (const uint8_t*)whhb;
    uint8_t*       hbp = hb2;
    void* args[4] = {(void*)&p2p, (void*)&tkp, (void*)&whp, (void*)&hbp};
    hipError_t e = hipLaunchCooperativeKernel((void*)k_lstm, dim3(256), dim3(256),
                                              args, 0, stream);
    if (e != hipSuccess) {
      (void)hipGetLastError();  // clear; fall back (256 blocks @ 1/CU are co-resident)
      k_lstm<<<256, 256, 0, stream>>>(p2p, tkp, whp, hbp);
    }
  }

  k_fc<<<256, 64, 0, stream>>>(hb2, wfc, bfc, out);
}

// Round 5
// 2185.438 us; speedup vs baseline: 1.2800x; 1.2800x over previous
//
#include <hip/hip_runtime.h>
#include <stdint.h>

// Problem constants
#define VOCAB  50000
#define EMBD   256
#define HIDD   512
#define G4     2048   // 4*HID
#define NBAT   256
#define TSEQ   512

// ---- workspace layout (bytes) ----
#define O_P2    0ull            // P2[v][j*4+g] bf16 : VOCAB*G4*2      = 204,800,000
#define O_EMBT  204800000ull    // emb bf16 [V][E] (dead after k_proj; flags live here)
#define O_WIH   230400000ull    // W_ih bf16 [G4][E]
#define O_WHH   231448576ull    // W_hh bf16 [G4][H]
#define O_TOKT  233545728ull    // tokT int [2][T][N]
#define O_HBUF  234594304ull    // h bf16 [2 lstm][2 phase][N][H] = 1 MiB
#define WS_NEED 235643136ull
#define O_FLAGS O_EMBT          // 1024 wave-flags x 256B stride = 256 KB (embT dead)

typedef __bf16 bf16x8 __attribute__((ext_vector_type(8)));
typedef float  f32x4  __attribute__((ext_vector_type(4)));
typedef float  f32x16 __attribute__((ext_vector_type(16)));
typedef unsigned long long u64;

__device__ __forceinline__ unsigned short f2bf(float x) {
  unsigned u = __float_as_uint(x);
  u = (u + 0x7fffu + ((u >> 16) & 1u)) >> 16;   // RNE
  return (unsigned short)u;
}
__device__ __forceinline__ float b2f(unsigned short b) {
  return __uint_as_float(((unsigned)b) << 16);
}
__device__ __forceinline__ float sigf(float x) {
  float e = __builtin_amdgcn_exp2f(-1.4426950408889634f * x);
  return __builtin_amdgcn_rcpf(1.0f + e);
}
__device__ __forceinline__ float tanhf_(float x) {
  float e = __builtin_amdgcn_exp2f(-2.8853900817779268f * x);
  return 2.0f * __builtin_amdgcn_rcpf(1.0f + e) - 1.0f;
}

// ------------------------------------------------------------------
// K1: prep — bf16 converts, token transpose, zero h
// ------------------------------------------------------------------
__global__ void k_prep(const float* __restrict__ emb, const float* __restrict__ wih,
                       const float* __restrict__ whh, const int* __restrict__ tok1,
                       const int* __restrict__ tok2, unsigned short* __restrict__ embT,
                       unsigned short* __restrict__ wihb, unsigned short* __restrict__ whhb,
                       int* __restrict__ tokT, unsigned* __restrict__ hz)
{
  const int stride = gridDim.x * blockDim.x;
  const int id0 = blockIdx.x * blockDim.x + threadIdx.x;
  for (int i = id0; i < VOCAB * EMBD; i += stride) embT[i] = f2bf(emb[i]);
  for (int i = id0; i < G4 * EMBD; i += stride)    wihb[i] = f2bf(wih[i]);
  for (int i = id0; i < G4 * HIDD; i += stride)    whhb[i] = f2bf(whh[i]);
  for (int i = id0; i < 2 * TSEQ * NBAT; i += stride) {
    int l = i >> 17, t = (i >> 8) & 511, n = i & 255;
    tokT[i] = (l ? tok2 : tok1)[n * TSEQ + t];
  }
  for (int i = id0; i < 262144; i += stride) hz[i] = 0u;   // zero h buffers (1 MiB)
}

// ------------------------------------------------------------------
// K1b: zero wave-flags (runs after k_proj; flags overlap embT region)
// ------------------------------------------------------------------
__global__ void k_zero(unsigned* __restrict__ flags)
{
  const int i = blockIdx.x * blockDim.x + threadIdx.x;
  if (i < 65536) flags[i] = 0u;   // 256 KB
}

// ------------------------------------------------------------------
// K2: vocab projection  P2[v][j*4+g] = emb[v]·W_ih[g*512+j] + b_ih + b_hh
// (unchanged — correctness-verified)
// ------------------------------------------------------------------
__global__ __launch_bounds__(256) void
k_proj(const unsigned short* __restrict__ embT, const unsigned short* __restrict__ wihb,
       const float* __restrict__ bih, const float* __restrict__ bhh,
       unsigned short* __restrict__ P2)
{
  const int l  = threadIdx.x & 63;
  const int w  = threadIdx.x >> 6;
  const int n0 = blockIdx.x * 128 + (w & 1) * 64;
  const int m0 = blockIdx.y * 128 + (w >> 1) * 64;
  const int lq = l >> 4, lc = l & 15;

  f32x4 acc[4][4];
  #pragma unroll
  for (int a = 0; a < 4; ++a)
    #pragma unroll
    for (int b = 0; b < 4; ++b) acc[a][b] = (f32x4){0.f, 0.f, 0.f, 0.f};

  const uint8_t* eb = (const uint8_t*)embT;
  const uint8_t* wb = (const uint8_t*)wihb;
  #pragma unroll
  for (int ks = 0; ks < 8; ++ks) {
    const int koff = ks * 64 + lq * 16;
    bf16x8 a[4], b[4];
    #pragma unroll
    for (int mt = 0; mt < 4; ++mt) {
      int row = m0 + mt * 16 + lc; if (row >= VOCAB) row = VOCAB - 1;
      a[mt] = *(const bf16x8*)(eb + (size_t)row * 512 + koff);
    }
    #pragma unroll
    for (int nt = 0; nt < 4; ++nt) {
      int g = n0 + nt * 16 + lc;
      b[nt] = *(const bf16x8*)(wb + (size_t)g * 512 + koff);
    }
    #pragma unroll
    for (int mt = 0; mt < 4; ++mt)
      #pragma unroll
      for (int nt = 0; nt < 4; ++nt)
        acc[mt][nt] = __builtin_amdgcn_mfma_f32_16x16x32_bf16(a[mt], b[nt], acc[mt][nt], 0, 0, 0);
  }

  #pragma unroll
  for (int mt = 0; mt < 4; ++mt)
    #pragma unroll
    for (int r = 0; r < 4; ++r) {
      const int vrow = m0 + mt * 16 + lq * 4 + r;
      if (vrow < VOCAB) {
        #pragma unroll
        for (int nt = 0; nt < 4; ++nt) {
          const int gcol = n0 + nt * 16 + lc;
          float v = acc[mt][nt][r] + bih[gcol] + bhh[gcol];
          const int colp = ((gcol & 511) << 2) | (gcol >> 9);  // [j][g] permuted
          P2[(size_t)vrow * 2048 + colp] = f2bf(v);
        }
      }
    }
}

// ------------------------------------------------------------------
// K3: persistent LSTM scan. 256 blocks x 256 threads (4 waves).
// block = (lstm, mg: 32 batch rows, jb: 32 hidden cols). wave = gate.
// W_hh B-fragments in VGPRs (proven round 3). h exchange: agent-scope
// (MALL) 8B stores / loads, identical to the proven 1650us kernel.
// This round: DECENTRALIZED PER-WAVE FLAGS.
//   - 64 flags per group (16 blocks x 4 waves), 256B stride, agent scope.
//   - writer wave: epilogue stores -> own s_waitcnt vmcnt(0) -> lane0
//     publishes wave-flag = t+1. No B4 barrier, no centralized flag.
//   - every wave polls all 64 group flags itself (lane i <-> flag i,
//     4B loads: poll traffic stays flag-sized — round-4 lesson). No B1.
//   Safety: flag=t from wave Z => Z finished step t-1 epilogue => Z done
//   reading A-tile and gb => overwriting A/gb at step t is race-free.
//   B2 (A ready) and B3 (gb ready) remain: 2 barriers/step.
// LDS declared 160KB to FORCE 1 block/CU.
// ------------------------------------------------------------------
#define GB 32768    // LDS offset of f32 gate buffer (A-tile occupies [0,32768))

__global__ __launch_bounds__(256, 1) void
k_lstm(const uint8_t* __restrict__ P2, const int* __restrict__ tokT,
       const uint8_t* __restrict__ whh, uint8_t* __restrict__ hbuf,
       unsigned* __restrict__ flags)
{
  __shared__ __align__(16) uint8_t smem[163840];   // oversized on purpose: 1 block/CU
  const int tid  = threadIdx.x;
  const int l    = tid & 63;
  const int w    = tid >> 6;        // wave = gate index
  const int bid  = blockIdx.x;
  const int jb   = bid & 15;
  const int mg   = (bid >> 4) & 7;
  const int lstm = bid >> 7;
  const int grp  = bid >> 4;        // 0..15, 16 blocks each (lstm, mg)
  const int m0   = mg * 32;
  const int j0   = jb * 32;

  const size_t hslot = (size_t)NBAT * HIDD * 2;   // 262144 B
  const int em   = tid >> 3;        // epilogue batch row 0..31
  const int ecol = tid & 7;         // epilogue col group (4 cols)
  const int an   = l & 31;          // MFMA A-row / B-col (lane&31)
  const int ah   = l >> 5;          // k-half (lane>>5)

  // ---- load this lane's invariant W_hh B-fragments into registers ----
  bf16x8 wreg[32];
  {
    const uint8_t* wrow = whh + (size_t)(w * 512 + j0 + an) * 1024 + (size_t)ah * 16;
    #pragma unroll
    for (int ks = 0; ks < 32; ++ks)
      wreg[ks] = *(const bf16x8*)(wrow + ks * 32);
  }

  // wave-flag ids: group base grp*64; block jb contributes flags jb*4+w.
  // lane i polls flag (grp*64 + i)  — exactly the 64 flags of this group.
  const unsigned* fpoll = flags + (size_t)(grp * 64 + l) * 64;
  unsigned* fmine = flags + (size_t)(grp * 64 + jb * 4 + w) * 64;

  float cst[4] = {0.f, 0.f, 0.f, 0.f};
  int tok_next = tokT[(lstm * TSEQ + 0) * NBAT + m0 + em];

  for (int t = 0; t < TSEQ; ++t) {
    const int tok_cur = tok_next;

    // ---- issue xg gather + next-token load FIRST (hides under the poll) ----
    const uint8_t* xsrc = P2 + (size_t)tok_cur * 4096 + (size_t)j0 * 8 + (size_t)ecol * 32;
    const uint4 xq0 = *(const uint4*)(xsrc);
    const uint4 xq1 = *(const uint4*)(xsrc + 16);
    if (t + 1 < TSEQ) tok_next = tokT[(lstm * TSEQ + (t + 1)) * NBAT + m0 + em];

    // ---- every wave: wait for all 64 group wave-flags >= t ----
    if (t > 0) {
      const unsigned tgt = (unsigned)t;
      int guard = 0;
      for (;;) {
        const unsigned v = __hip_atomic_load(fpoll, __ATOMIC_RELAXED, __HIP_MEMORY_SCOPE_AGENT);
        if (__all((int)(v >= tgt))) break;
        __builtin_amdgcn_s_sleep(1);
        if (++guard > 400000) break;           // fail visible, not hung
      }
    }
    // no barrier: peer flag >= t proves that wave finished its step t-1
    // A-tile/gb reads, so staging below cannot race.

    // ---- stage h tile (32 rows x 1KB) via agent-scope atomic loads ----
    {
      const uint8_t* hb = hbuf + (size_t)(lstm * 2 + (t & 1)) * hslot
                        + (size_t)m0 * 1024 + (size_t)tid * 8;
      u64 v[16];
      #pragma unroll
      for (int i = 0; i < 16; ++i)
        v[i] = __hip_atomic_load((const u64*)(hb + (size_t)i * 2048),
                                 __ATOMIC_RELAXED, __HIP_MEMORY_SCOPE_AGENT);
      #pragma unroll
      for (int i = 0; i < 16; ++i) {
        const int m = i * 2 + (tid >> 7);
        const int c = (tid >> 1) & 63;
        const int half = tid & 1;
        *(u64*)(smem + (size_t)m * 1024 + ((c ^ (m & 7)) * 16) + half * 8) = v[i];
      }
    }
    __syncthreads();   // B2: h LDS ready

    // ---- GEMM: gate_w[32x32] = h[32x512] . W_g[32x512]^T (32x32x16 MFMA) ----
    f32x16 acc0{}, acc1{};
    #pragma unroll
    for (int ks = 0; ks < 32; ++ks) {
      const int ch = ks * 2 + ah;
      const bf16x8 av = *(const bf16x8*)(smem + (size_t)an * 1024 + ((ch ^ (an & 7)) * 16));
      if (ks & 1) acc1 = __builtin_amdgcn_mfma_f32_32x32x16_bf16(av, wreg[ks], acc1, 0, 0, 0);
      else        acc0 = __builtin_amdgcn_mfma_f32_32x32x16_bf16(av, wreg[ks], acc0, 0, 0, 0);
    }
    // gate writes go to GB region (disjoint from A) -> no barrier needed here

    {
      float* gb = (float*)(smem + GB);   // gbuf[g][row 0..31][col 0..31] f32
      #pragma unroll
      for (int r = 0; r < 16; ++r) {
        const int row = (r & 3) + 8 * (r >> 2) + 4 * ah;   // 32x32 C/D mapping
        gb[w * 1024 + row * 32 + an] = acc0[r] + acc1[r];
      }
    }
    __syncthreads();   // B3: gate buffer ready

    // ---- epilogue: 4 cells/lane, nonlinearity, h -> MALL; per-wave flag ----
    {
      const float* gb = (const float*)(smem + GB);
      const f32x4 pi = *(const f32x4*)(gb + 0 * 1024 + em * 32 + ecol * 4);
      const f32x4 pf = *(const f32x4*)(gb + 1 * 1024 + em * 32 + ecol * 4);
      const f32x4 pg = *(const f32x4*)(gb + 2 * 1024 + em * 32 + ecol * 4);
      const f32x4 po = *(const f32x4*)(gb + 3 * 1024 + em * 32 + ecol * 4);
      unsigned short xsv[16];
      *(uint4*)(xsv) = xq0;
      *(uint4*)(xsv + 8) = xq1;
      unsigned short hv[4];
      #pragma unroll
      for (int k = 0; k < 4; ++k) {
        const float iv = sigf(pi[k] + b2f(xsv[k * 4 + 0]));
        const float fv = sigf(pf[k] + b2f(xsv[k * 4 + 1]));
        const float gv = tanhf_(pg[k] + b2f(xsv[k * 4 + 2]));
        const float ov = sigf(po[k] + b2f(xsv[k * 4 + 3]));
        const float cv = fv * cst[k] + iv * gv;
        cst[k] = cv;
        hv[k] = f2bf(ov * tanhf_(cv));
      }
      const u64 hp = (u64)hv[0] | ((u64)hv[1] << 16) | ((u64)hv[2] << 32) | ((u64)hv[3] << 48);
      uint8_t* hdst = hbuf + (size_t)(lstm * 2 + ((t + 1) & 1)) * hslot
                    + (size_t)(m0 + em) * 1024 + (size_t)(j0 + ecol * 4) * 2;
      __hip_atomic_store((u64*)hdst, hp, __ATOMIC_RELAXED, __HIP_MEMORY_SCOPE_AGENT);
    }
    // drain THIS WAVE's h stores, then publish this wave's flag.
    asm volatile("s_waitcnt vmcnt(0)" ::: "memory");
    if (l == 0 && t + 1 < TSEQ)
      __hip_atomic_store(fmine, (unsigned)(t + 1),
                         __ATOMIC_RELAXED, __HIP_MEMORY_SCOPE_AGENT);
  }
}

// ------------------------------------------------------------------
// K4: h1*h2 -> logits -> softmax. one wave per batch row.
// ------------------------------------------------------------------
__global__ __launch_bounds__(64) void
k_fc(const uint8_t* __restrict__ hbuf, const float* __restrict__ wfc,
     const float* __restrict__ bfc, float* __restrict__ out)
{
  const int n = blockIdx.x, l = threadIdx.x;
  const unsigned short* h1 = (const unsigned short*)(hbuf) + (size_t)n * HIDD;
  const unsigned short* h2 = (const unsigned short*)(hbuf + 2 * (size_t)NBAT * HIDD * 2) + (size_t)n * HIDD;
  float s0 = 0.f, s1 = 0.f;
  for (int j = l; j < HIDD; j += 64) {
    float hv = b2f(h1[j]) * b2f(h2[j]);
    s0 += hv * wfc[j];
    s1 += hv * wfc[HIDD + j];
  }
  #pragma unroll
  for (int off = 32; off > 0; off >>= 1) {
    s0 += __shfl_down(s0, off, 64);
    s1 += __shfl_down(s1, off, 64);
  }
  if (l == 0) {
    s0 += bfc[0]; s1 += bfc[1];
    float m  = fmaxf(s0, s1);
    float e0 = __builtin_amdgcn_exp2f((s0 - m) * 1.4426950408889634f);
    float e1 = __builtin_amdgcn_exp2f((s1 - m) * 1.4426950408889634f);
    float inv = 1.0f / (e0 + e1);
    out[n * 2 + 0] = e0 * inv;
    out[n * 2 + 1] = e1 * inv;
  }
}

// ------------------------------------------------------------------
extern "C" void kernel_launch(void* const* d_in, const int* in_sizes, int n_in,
                              void* d_out, int out_size, void* d_ws, size_t ws_size,
                              hipStream_t stream) {
  (void)in_sizes; (void)n_in; (void)out_size;
  if (ws_size < WS_NEED) return;   // fail visibly rather than scribble OOB

  const int*   tok1 = (const int*)d_in[0];
  const int*   tok2 = (const int*)d_in[1];
  const float* emb  = (const float*)d_in[2];
  const float* wih  = (const float*)d_in[3];
  const float* whh  = (const float*)d_in[4];
  const float* bih  = (const float*)d_in[5];
  const float* bhh  = (const float*)d_in[6];
  const float* wfc  = (const float*)d_in[7];
  const float* bfc  = (const float*)d_in[8];
  float* out = (float*)d_out;

  uint8_t* ws = (uint8_t*)d_ws;
  unsigned short* P2    = (unsigned short*)(ws + O_P2);
  unsigned short* embT  = (unsigned short*)(ws + O_EMBT);
  unsigned short* wihb  = (unsigned short*)(ws + O_WIH);
  unsigned short* whhb  = (unsigned short*)(ws + O_WHH);
  int*            tokT  = (int*)(ws + O_TOKT);
  uint8_t*        hbuf  = ws + O_HBUF;
  unsigned*       flags = (unsigned*)(ws + O_FLAGS);

  k_prep<<<1024, 256, 0, stream>>>(emb, wih, whh, tok1, tok2, embT, wihb, whhb,
                                   tokT, (unsigned*)hbuf);
  k_proj<<<dim3(16, 391), 256, 0, stream>>>(embT, wihb, bih, bhh, P2);
  k_zero<<<256, 256, 0, stream>>>(flags);   // embT dead after k_proj; flags live there

  {
    const uint8_t* p2p = (const uint8_t*)P2;
    const int*     tkp = tokT;
    const uint8_t* whp = (const uint8_t*)whhb;
    uint8_t*       hbp = hbuf;
    unsigned*      flp = flags;
    void* args[5] = {(void*)&p2p, (void*)&tkp, (void*)&whp, (void*)&hbp, (void*)&flp};
    hipError_t e = hipLaunchCooperativeKernel((void*)k_lstm, dim3(256), dim3(256),
                                              args, 0, stream);
    if (e != hipSuccess) {
      (void)hipGetLastError();  // clear; fall back (256 blocks @ 1/CU are co-resident)
      k_lstm<<<256, 256, 0, stream>>>(p2p, tkp, whp, hbp, flp);
    }
  }

  k_fc<<<256, 64, 0, stream>>>(hbuf, wfc, bfc, out);
}

// Round 6
// 2176.307 us; speedup vs baseline: 1.2853x; 1.0042x over previous
//
#include <hip/hip_runtime.h>
#include <stdint.h>

// Problem constants
#define VOCAB  50000
#define EMBD   256
#define HIDD   512
#define G4     2048   // 4*HID
#define NBAT   256
#define TSEQ   512

// ---- workspace layout (bytes) ----
#define O_P2    0ull            // P2[v][j*4+g] bf16 : VOCAB*G4*2      = 204,800,000
#define O_EMBT  204800000ull    // emb bf16 [V][E] (dead after k_proj; flags live here)
#define O_WIH   230400000ull    // W_ih bf16 [G4][E]
#define O_WHH   231448576ull    // W_hh bf16 [G4][H]
#define O_TOKT  233545728ull    // tokT int [2][T][N]
#define O_HBUF  234594304ull    // h bf16 [2 lstm][2 phase][N][H] = 1 MiB
#define WS_NEED 235643136ull
#define O_FLAGS O_EMBT          // 256 flags x 256B stride = 64 KB (embT dead)

typedef __bf16 bf16x8 __attribute__((ext_vector_type(8)));
typedef float  f32x4  __attribute__((ext_vector_type(4)));
typedef float  f32x16 __attribute__((ext_vector_type(16)));
typedef unsigned long long u64;

__device__ __forceinline__ unsigned short f2bf(float x) {
  unsigned u = __float_as_uint(x);
  u = (u + 0x7fffu + ((u >> 16) & 1u)) >> 16;   // RNE
  return (unsigned short)u;
}
__device__ __forceinline__ float b2f(unsigned short b) {
  return __uint_as_float(((unsigned)b) << 16);
}
__device__ __forceinline__ float sigf(float x) {
  float e = __builtin_amdgcn_exp2f(-1.4426950408889634f * x);
  return __builtin_amdgcn_rcpf(1.0f + e);
}
__device__ __forceinline__ float tanhf_(float x) {
  float e = __builtin_amdgcn_exp2f(-2.8853900817779268f * x);
  return 2.0f * __builtin_amdgcn_rcpf(1.0f + e) - 1.0f;
}

// ------------------------------------------------------------------
// K1: prep — bf16 converts, token transpose, zero h
// ------------------------------------------------------------------
__global__ void k_prep(const float* __restrict__ emb, const float* __restrict__ wih,
                       const float* __restrict__ whh, const int* __restrict__ tok1,
                       const int* __restrict__ tok2, unsigned short* __restrict__ embT,
                       unsigned short* __restrict__ wihb, unsigned short* __restrict__ whhb,
                       int* __restrict__ tokT, unsigned* __restrict__ hz)
{
  const int stride = gridDim.x * blockDim.x;
  const int id0 = blockIdx.x * blockDim.x + threadIdx.x;
  for (int i = id0; i < VOCAB * EMBD; i += stride) embT[i] = f2bf(emb[i]);
  for (int i = id0; i < G4 * EMBD; i += stride)    wihb[i] = f2bf(wih[i]);
  for (int i = id0; i < G4 * HIDD; i += stride)    whhb[i] = f2bf(whh[i]);
  for (int i = id0; i < 2 * TSEQ * NBAT; i += stride) {
    int l = i >> 17, t = (i >> 8) & 511, n = i & 255;
    tokT[i] = (l ? tok2 : tok1)[n * TSEQ + t];
  }
  for (int i = id0; i < 262144; i += stride) hz[i] = 0u;   // zero h buffers (1 MiB)
}

// ------------------------------------------------------------------
// K1b: zero block-flags (runs after k_proj; flags overlap embT region)
// ------------------------------------------------------------------
__global__ void k_zero(unsigned* __restrict__ flags)
{
  const int i = blockIdx.x * blockDim.x + threadIdx.x;
  if (i < 16384) flags[i] = 0u;   // 64 KB
}

// ------------------------------------------------------------------
// K2: vocab projection  P2[v][j*4+g] = emb[v]·W_ih[g*512+j] + b_ih + b_hh
// (unchanged — correctness-verified)
// ------------------------------------------------------------------
__global__ __launch_bounds__(256) void
k_proj(const unsigned short* __restrict__ embT, const unsigned short* __restrict__ wihb,
       const float* __restrict__ bih, const float* __restrict__ bhh,
       unsigned short* __restrict__ P2)
{
  const int l  = threadIdx.x & 63;
  const int w  = threadIdx.x >> 6;
  const int n0 = blockIdx.x * 128 + (w & 1) * 64;
  const int m0 = blockIdx.y * 128 + (w >> 1) * 64;
  const int lq = l >> 4, lc = l & 15;

  f32x4 acc[4][4];
  #pragma unroll
  for (int a = 0; a < 4; ++a)
    #pragma unroll
    for (int b = 0; b < 4; ++b) acc[a][b] = (f32x4){0.f, 0.f, 0.f, 0.f};

  const uint8_t* eb = (const uint8_t*)embT;
  const uint8_t* wb = (const uint8_t*)wihb;
  #pragma unroll
  for (int ks = 0; ks < 8; ++ks) {
    const int koff = ks * 64 + lq * 16;
    bf16x8 a[4], b[4];
    #pragma unroll
    for (int mt = 0; mt < 4; ++mt) {
      int row = m0 + mt * 16 + lc; if (row >= VOCAB) row = VOCAB - 1;
      a[mt] = *(const bf16x8*)(eb + (size_t)row * 512 + koff);
    }
    #pragma unroll
    for (int nt = 0; nt < 4; ++nt) {
      int g = n0 + nt * 16 + lc;
      b[nt] = *(const bf16x8*)(wb + (size_t)g * 512 + koff);
    }
    #pragma unroll
    for (int mt = 0; mt < 4; ++mt)
      #pragma unroll
      for (int nt = 0; nt < 4; ++nt)
        acc[mt][nt] = __builtin_amdgcn_mfma_f32_16x16x32_bf16(a[mt], b[nt], acc[mt][nt], 0, 0, 0);
  }

  #pragma unroll
  for (int mt = 0; mt < 4; ++mt)
    #pragma unroll
    for (int r = 0; r < 4; ++r) {
      const int vrow = m0 + mt * 16 + lq * 4 + r;
      if (vrow < VOCAB) {
        #pragma unroll
        for (int nt = 0; nt < 4; ++nt) {
          const int gcol = n0 + nt * 16 + lc;
          float v = acc[mt][nt][r] + bih[gcol] + bhh[gcol];
          const int colp = ((gcol & 511) << 2) | (gcol >> 9);  // [j][g] permuted
          P2[(size_t)vrow * 2048 + colp] = f2bf(v);
        }
      }
    }
}

// ------------------------------------------------------------------
// K3: persistent LSTM scan. 256 blocks x 256 threads (4 waves).
// block = (lstm, mg: 32 batch rows, jb: 32 hidden cols). wave = gate.
// W_hh B-fragments in VGPRs (round 3, proven). Poll: w0-only, 16 block
// flags + B1 (round 3, proven — per round-5 lesson poll traffic must
// stay 1 wave / flag-sized).
// This round vs round 3:
//  (a) B4 removed: each wave drains its OWN h stores (vmcnt(0)), bumps
//      an LDS counter; the LAST wave (old == 4t+3) publishes the block
//      flag. Release-safe: last incrementer runs only after all waves
//      executed their own drains. Region reuse stays fenced by B1.
//  (b) staging: 8 x 16B global_load_dwordx4 sc0 sc1 (L1+L2 bypass)
//      instead of 16 x 8B agent atomics. Atomicity not needed after
//      the flag handshake; hbuf is only ever touched by bypassing ops
//      inside this kernel, so no stale cache copy can exist.
// Barriers/step: B1, B2, B3.
// LDS declared 160KB to FORCE 1 block/CU.
// ------------------------------------------------------------------
#define GB  32768    // LDS offset of f32 gate buffer (A-tile occupies [0,32768))
#define CNT 49152    // LDS offset of wave-completion counter (u32)

__global__ __launch_bounds__(256, 1) void
k_lstm(const uint8_t* __restrict__ P2, const int* __restrict__ tokT,
       const uint8_t* __restrict__ whh, uint8_t* __restrict__ hbuf,
       unsigned* __restrict__ flags)
{
  __shared__ __align__(16) uint8_t smem[163840];   // oversized on purpose: 1 block/CU
  const int tid  = threadIdx.x;
  const int l    = tid & 63;
  const int w    = tid >> 6;        // wave = gate index
  const int bid  = blockIdx.x;
  const int jb   = bid & 15;
  const int mg   = (bid >> 4) & 7;
  const int lstm = bid >> 7;
  const int grp  = bid >> 4;        // 0..15, 16 blocks each (lstm, mg)
  const int m0   = mg * 32;
  const int j0   = jb * 32;

  const size_t hslot = (size_t)NBAT * HIDD * 2;   // 262144 B
  const int em   = tid >> 3;        // epilogue batch row 0..31
  const int ecol = tid & 7;         // epilogue col group (4 cols)
  const int an   = l & 31;          // MFMA A-row / B-col (lane&31)
  const int ah   = l >> 5;          // k-half (lane>>5)

  if (tid == 0) *(volatile unsigned*)(smem + CNT) = 0u;   // wave counter

  // ---- load this lane's invariant W_hh B-fragments into registers ----
  bf16x8 wreg[32];
  {
    const uint8_t* wrow = whh + (size_t)(w * 512 + j0 + an) * 1024 + (size_t)ah * 16;
    #pragma unroll
    for (int ks = 0; ks < 32; ++ks)
      wreg[ks] = *(const bf16x8*)(wrow + ks * 32);
  }

  // poll address: lane i (i<16) watches peer (grp*16 + i)'s flag (256B stride)
  const unsigned* fpoll = flags + (size_t)(grp * 16 + (l & 15)) * 64;
  unsigned* fmine = flags + (size_t)bid * 64;

  float cst[4] = {0.f, 0.f, 0.f, 0.f};
  int tok_next = tokT[(lstm * TSEQ + 0) * NBAT + m0 + em];

  for (int t = 0; t < TSEQ; ++t) {
    const int tok_cur = tok_next;

    // ---- issue xg gather + next-token load FIRST (hides under the poll) ----
    const uint8_t* xsrc = P2 + (size_t)tok_cur * 4096 + (size_t)j0 * 8 + (size_t)ecol * 32;
    const uint4 xq0 = *(const uint4*)(xsrc);
    const uint4 xq1 = *(const uint4*)(xsrc + 16);
    if (t + 1 < TSEQ) tok_next = tokT[(lstm * TSEQ + (t + 1)) * NBAT + m0 + em];

    // ---- w0 waits for all 16 peer blocks past step t-1 (1 wave, 16 lines) ----
    if (t > 0 && w == 0) {
      const unsigned tgt = (unsigned)t;
      int guard = 0;
      for (;;) {
        const unsigned v = __hip_atomic_load(fpoll, __ATOMIC_RELAXED, __HIP_MEMORY_SCOPE_AGENT);
        if (__all((int)(v >= tgt))) break;
        __builtin_amdgcn_s_sleep(1);
        if (++guard > 400000) break;           // fail visible, not hung
      }
    }
    __syncthreads();   // B1: all waves past poll; LDS A-region free for reuse

    // ---- stage h tile (32 rows x 1KB): 8 x 16B L1/L2-bypass loads ----
    {
      const uint8_t* hb = hbuf + (size_t)(lstm * 2 + (t & 1)) * hslot
                        + (size_t)m0 * 1024
                        + (size_t)(tid >> 7) * 2048 + (size_t)(tid & 127) * 16;
      uint4 v[8];
      #pragma unroll
      for (int i = 0; i < 8; ++i)
        asm volatile("global_load_dwordx4 %0, %1, off sc0 sc1"
                     : "=v"(v[i]) : "v"(hb + (size_t)i * 4096));
      asm volatile("s_waitcnt vmcnt(0)" ::: "memory");
      __builtin_amdgcn_sched_barrier(0);
      const int c16 = tid & 63;
      #pragma unroll
      for (int i = 0; i < 8; ++i) {
        const int m = i * 4 + 2 * (tid >> 7) + ((tid >> 6) & 1);
        *(uint4*)(smem + (size_t)m * 1024 + ((c16 ^ (m & 7)) * 16)) = v[i];
      }
    }
    __syncthreads();   // B2: h LDS ready

    // ---- GEMM: gate_w[32x32] = h[32x512] . W_g[32x512]^T (32x32x16 MFMA) ----
    f32x16 acc0{}, acc1{};
    #pragma unroll
    for (int ks = 0; ks < 32; ++ks) {
      const int ch = ks * 2 + ah;
      const bf16x8 av = *(const bf16x8*)(smem + (size_t)an * 1024 + ((ch ^ (an & 7)) * 16));
      if (ks & 1) acc1 = __builtin_amdgcn_mfma_f32_32x32x16_bf16(av, wreg[ks], acc1, 0, 0, 0);
      else        acc0 = __builtin_amdgcn_mfma_f32_32x32x16_bf16(av, wreg[ks], acc0, 0, 0, 0);
    }
    // gate writes go to GB region (disjoint from A) -> no barrier needed here

    {
      float* gb = (float*)(smem + GB);   // gbuf[g][row 0..31][col 0..31] f32
      #pragma unroll
      for (int r = 0; r < 16; ++r) {
        const int row = (r & 3) + 8 * (r >> 2) + 4 * ah;   // 32x32 C/D mapping
        gb[w * 1024 + row * 32 + an] = acc0[r] + acc1[r];
      }
    }
    __syncthreads();   // B3: gate buffer ready

    // ---- epilogue: 4 cells/lane, nonlinearity, h -> MALL ----
    {
      const float* gb = (const float*)(smem + GB);
      const f32x4 pi = *(const f32x4*)(gb + 0 * 1024 + em * 32 + ecol * 4);
      const f32x4 pf = *(const f32x4*)(gb + 1 * 1024 + em * 32 + ecol * 4);
      const f32x4 pg = *(const f32x4*)(gb + 2 * 1024 + em * 32 + ecol * 4);
      const f32x4 po = *(const f32x4*)(gb + 3 * 1024 + em * 32 + ecol * 4);
      unsigned short xsv[16];
      *(uint4*)(xsv) = xq0;
      *(uint4*)(xsv + 8) = xq1;
      unsigned short hv[4];
      #pragma unroll
      for (int k = 0; k < 4; ++k) {
        const float iv = sigf(pi[k] + b2f(xsv[k * 4 + 0]));
        const float fv = sigf(pf[k] + b2f(xsv[k * 4 + 1]));
        const float gv = tanhf_(pg[k] + b2f(xsv[k * 4 + 2]));
        const float ov = sigf(po[k] + b2f(xsv[k * 4 + 3]));
        const float cv = fv * cst[k] + iv * gv;
        cst[k] = cv;
        hv[k] = f2bf(ov * tanhf_(cv));
      }
      const u64 hp = (u64)hv[0] | ((u64)hv[1] << 16) | ((u64)hv[2] << 32) | ((u64)hv[3] << 48);
      uint8_t* hdst = hbuf + (size_t)(lstm * 2 + ((t + 1) & 1)) * hslot
                    + (size_t)(m0 + em) * 1024 + (size_t)(j0 + ecol * 4) * 2;
      __hip_atomic_store((u64*)hdst, hp, __ATOMIC_RELAXED, __HIP_MEMORY_SCOPE_AGENT);
    }

    // ---- per-wave drain; LAST wave (LDS counter) publishes block flag ----
    asm volatile("s_waitcnt vmcnt(0)" ::: "memory");
    if (l == 0 && t + 1 < TSEQ) {
      const unsigned old = atomicAdd((unsigned*)(smem + CNT), 1u);
      if (old == (unsigned)(4 * t + 3))   // all 4 waves drained this step
        __hip_atomic_store(fmine, (unsigned)(t + 1),
                           __ATOMIC_RELAXED, __HIP_MEMORY_SCOPE_AGENT);
    }
  }
}

// ------------------------------------------------------------------
// K4: h1*h2 -> logits -> softmax. one wave per batch row.
// ------------------------------------------------------------------
__global__ __launch_bounds__(64) void
k_fc(const uint8_t* __restrict__ hbuf, const float* __restrict__ wfc,
     const float* __restrict__ bfc, float* __restrict__ out)
{
  const int n = blockIdx.x, l = threadIdx.x;
  const unsigned short* h1 = (const unsigned short*)(hbuf) + (size_t)n * HIDD;
  const unsigned short* h2 = (const unsigned short*)(hbuf + 2 * (size_t)NBAT * HIDD * 2) + (size_t)n * HIDD;
  float s0 = 0.f, s1 = 0.f;
  for (int j = l; j < HIDD; j += 64) {
    float hv = b2f(h1[j]) * b2f(h2[j]);
    s0 += hv * wfc[j];
    s1 += hv * wfc[HIDD + j];
  }
  #pragma unroll
  for (int off = 32; off > 0; off >>= 1) {
    s0 += __shfl_down(s0, off, 64);
    s1 += __shfl_down(s1, off, 64);
  }
  if (l == 0) {
    s0 += bfc[0]; s1 += bfc[1];
    float m  = fmaxf(s0, s1);
    float e0 = __builtin_amdgcn_exp2f((s0 - m) * 1.4426950408889634f);
    float e1 = __builtin_amdgcn_exp2f((s1 - m) * 1.4426950408889634f);
    float inv = 1.0f / (e0 + e1);
    out[n * 2 + 0] = e0 * inv;
    out[n * 2 + 1] = e1 * inv;
  }
}

// ------------------------------------------------------------------
extern "C" void kernel_launch(void* const* d_in, const int* in_sizes, int n_in,
                              void* d_out, int out_size, void* d_ws, size_t ws_size,
                              hipStream_t stream) {
  (void)in_sizes; (void)n_in; (void)out_size;
  if (ws_size < WS_NEED) return;   // fail visibly rather than scribble OOB

  const int*   tok1 = (const int*)d_in[0];
  const int*   tok2 = (const int*)d_in[1];
  const float* emb  = (const float*)d_in[2];
  const float* wih  = (const float*)d_in[3];
  const float* whh  = (const float*)d_in[4];
  const float* bih  = (const float*)d_in[5];
  const float* bhh  = (const float*)d_in[6];
  const float* wfc  = (const float*)d_in[7];
  const float* bfc  = (const float*)d_in[8];
  float* out = (float*)d_out;

  uint8_t* ws = (uint8_t*)d_ws;
  unsigned short* P2    = (unsigned short*)(ws + O_P2);
  unsigned short* embT  = (unsigned short*)(ws + O_EMBT);
  unsigned short* wihb  = (unsigned short*)(ws + O_WIH);
  unsigned short* whhb  = (unsigned short*)(ws + O_WHH);
  int*            tokT  = (int*)(ws + O_TOKT);
  uint8_t*        hbuf  = ws + O_HBUF;
  unsigned*       flags = (unsigned*)(ws + O_FLAGS);

  k_prep<<<1024, 256, 0, stream>>>(emb, wih, whh, tok1, tok2, embT, wihb, whhb,
                                   tokT, (unsigned*)hbuf);
  k_proj<<<dim3(16, 391), 256, 0, stream>>>(embT, wihb, bih, bhh, P2);
  k_zero<<<64, 256, 0, stream>>>(flags);   // embT dead after k_proj; flags live there

  {
    const uint8_t* p2p = (const uint8_t*)P2;
    const int*     tkp = tokT;
    const uint8_t* whp = (const uint8_t*)whhb;
    uint8_t*       hbp = hbuf;
    unsigned*      flp = flags;
    void* args[5] = {(void*)&p2p, (void*)&tkp, (void*)&whp, (void*)&hbp, (void*)&flp};
    hipError_t e = hipLaunchCooperativeKernel((void*)k_lstm, dim3(256), dim3(256),
                                              args, 0, stream);
    if (e != hipSuccess) {
      (void)hipGetLastError();  // clear; fall back (256 blocks @ 1/CU are co-resident)
      k_lstm<<<256, 256, 0, stream>>>(p2p, tkp, whp, hbp, flp);
    }
  }

  k_fc<<<256, 64, 0, stream>>>(hbuf, wfc, bfc, out);
}

// Round 7
// 1961.531 us; speedup vs baseline: 1.4261x; 1.1095x over previous
//
#include <hip/hip_runtime.h>
#include <stdint.h>

// Problem constants
#define VOCAB  50000
#define EMBD   256
#define HIDD   512
#define G4     2048   // 4*HID
#define NBAT   256
#define TSEQ   512

// ---- workspace layout (bytes) ----
#define O_P2    0ull            // P2[v][j*4+g] bf16 : VOCAB*G4*2      = 204,800,000
#define O_EMBT  204800000ull    // emb bf16 [V][E] (dead after k_proj; flags live here)
#define O_WIH   230400000ull    // W_ih bf16 [G4][E]
#define O_WHH   231448576ull    // W_hh bf16 [G4][H]
#define O_TOKT  233545728ull    // tokT int [2][T][N]
#define O_HBUF  234594304ull    // h bf16 [2 lstm][2 phase][N][H] = 1 MiB
#define WS_NEED 235643136ull
#define O_FLAGS O_EMBT          // 256 flags x 256B stride = 64 KB, zeroed post-k_proj

typedef __bf16 bf16x8 __attribute__((ext_vector_type(8)));
typedef float  f32x4  __attribute__((ext_vector_type(4)));
typedef float  f32x16 __attribute__((ext_vector_type(16)));
typedef unsigned long long u64;

__device__ __forceinline__ unsigned short f2bf(float x) {
  unsigned u = __float_as_uint(x);
  u = (u + 0x7fffu + ((u >> 16) & 1u)) >> 16;   // RNE
  return (unsigned short)u;
}
__device__ __forceinline__ float b2f(unsigned short b) {
  return __uint_as_float(((unsigned)b) << 16);
}
__device__ __forceinline__ float sigf(float x) {
  float e = __builtin_amdgcn_exp2f(-1.4426950408889634f * x);
  return __builtin_amdgcn_rcpf(1.0f + e);
}
__device__ __forceinline__ float tanhf_(float x) {
  float e = __builtin_amdgcn_exp2f(-2.8853900817779268f * x);
  return 2.0f * __builtin_amdgcn_rcpf(1.0f + e) - 1.0f;
}

// ------------------------------------------------------------------
// K1: prep — bf16 converts, token transpose, zero h
// ------------------------------------------------------------------
__global__ void k_prep(const float* __restrict__ emb, const float* __restrict__ wih,
                       const float* __restrict__ whh, const int* __restrict__ tok1,
                       const int* __restrict__ tok2, unsigned short* __restrict__ embT,
                       unsigned short* __restrict__ wihb, unsigned short* __restrict__ whhb,
                       int* __restrict__ tokT, unsigned* __restrict__ hz)
{
  const int stride = gridDim.x * blockDim.x;
  const int id0 = blockIdx.x * blockDim.x + threadIdx.x;
  for (int i = id0; i < VOCAB * EMBD; i += stride) embT[i] = f2bf(emb[i]);
  for (int i = id0; i < G4 * EMBD; i += stride)    wihb[i] = f2bf(wih[i]);
  for (int i = id0; i < G4 * HIDD; i += stride)    whhb[i] = f2bf(whh[i]);
  for (int i = id0; i < 2 * TSEQ * NBAT; i += stride) {
    int l = i >> 17, t = (i >> 8) & 511, n = i & 255;
    tokT[i] = (l ? tok2 : tok1)[n * TSEQ + t];
  }
  for (int i = id0; i < 262144; i += stride) hz[i] = 0u;   // zero h buffers (1 MiB)
}

// ------------------------------------------------------------------
// K1b: zero progress flags (runs after k_proj; flags overlap embT region)
// ------------------------------------------------------------------
__global__ void k_zero(unsigned* __restrict__ flags)
{
  const int i = blockIdx.x * blockDim.x + threadIdx.x;
  if (i < 16384) flags[i] = 0u;   // 64 KB
}

// ------------------------------------------------------------------
// K2: vocab projection  P2[v][j*4+g] = emb[v]·W_ih[g*512+j] + b_ih + b_hh
// (unchanged — correctness-verified)
// ------------------------------------------------------------------
__global__ __launch_bounds__(256) void
k_proj(const unsigned short* __restrict__ embT, const unsigned short* __restrict__ wihb,
       const float* __restrict__ bih, const float* __restrict__ bhh,
       unsigned short* __restrict__ P2)
{
  const int l  = threadIdx.x & 63;
  const int w  = threadIdx.x >> 6;
  const int n0 = blockIdx.x * 128 + (w & 1) * 64;
  const int m0 = blockIdx.y * 128 + (w >> 1) * 64;
  const int lq = l >> 4, lc = l & 15;

  f32x4 acc[4][4];
  #pragma unroll
  for (int a = 0; a < 4; ++a)
    #pragma unroll
    for (int b = 0; b < 4; ++b) acc[a][b] = (f32x4){0.f, 0.f, 0.f, 0.f};

  const uint8_t* eb = (const uint8_t*)embT;
  const uint8_t* wb = (const uint8_t*)wihb;
  #pragma unroll
  for (int ks = 0; ks < 8; ++ks) {
    const int koff = ks * 64 + lq * 16;
    bf16x8 a[4], b[4];
    #pragma unroll
    for (int mt = 0; mt < 4; ++mt) {
      int row = m0 + mt * 16 + lc; if (row >= VOCAB) row = VOCAB - 1;
      a[mt] = *(const bf16x8*)(eb + (size_t)row * 512 + koff);
    }
    #pragma unroll
    for (int nt = 0; nt < 4; ++nt) {
      int g = n0 + nt * 16 + lc;
      b[nt] = *(const bf16x8*)(wb + (size_t)g * 512 + koff);
    }
    #pragma unroll
    for (int mt = 0; mt < 4; ++mt)
      #pragma unroll
      for (int nt = 0; nt < 4; ++nt)
        acc[mt][nt] = __builtin_amdgcn_mfma_f32_16x16x32_bf16(a[mt], b[nt], acc[mt][nt], 0, 0, 0);
  }

  #pragma unroll
  for (int mt = 0; mt < 4; ++mt)
    #pragma unroll
    for (int r = 0; r < 4; ++r) {
      const int vrow = m0 + mt * 16 + lq * 4 + r;
      if (vrow < VOCAB) {
        #pragma unroll
        for (int nt = 0; nt < 4; ++nt) {
          const int gcol = n0 + nt * 16 + lc;
          float v = acc[mt][nt][r] + bih[gcol] + bhh[gcol];
          const int colp = ((gcol & 511) << 2) | (gcol >> 9);  // [j][g] permuted
          P2[(size_t)vrow * 2048 + colp] = f2bf(v);
        }
      }
    }
}

// ------------------------------------------------------------------
// K3: persistent LSTM scan. 256 blocks x 256 threads (4 waves).
// block = (lstm, mg: 32 batch rows, jb: 32 hidden cols). wave = gate.
// Sync: agent-scope (MALL) h/flag exchange — proven baseline protocol.
// W_hh B-fragments live in 128 VGPRs/lane (loaded once, statically
// indexed via full unroll) instead of LDS:
//   - GEMM LDS traffic per step halves (256 -> 128 KB)
//   - A-tile (32KB @ 0) and gate buffer (16KB @ 32768) are disjoint
// Empirical notes (R4-R6): protocol refactors all regress —
//   R4 fused data+flag packets: MALL traffic amplification (+834us)
//   R5 per-wave flags / all-wave poll: 4x poll transactions (+225us)
//   R6 last-wave flag + asm sc0sc1 staging: +210us
// Keep: w0-only 16-line poll, agent-atomic staging, 4 barriers.
// LDS declared 160KB to FORCE 1 block/CU (persistent-grid
// co-residency must not depend on the packer).
// ------------------------------------------------------------------
#define GB 32768    // LDS offset of f32 gate buffer (A-tile occupies [0,32768))

__global__ __launch_bounds__(256, 1) void
k_lstm(const uint8_t* __restrict__ P2, const int* __restrict__ tokT,
       const uint8_t* __restrict__ whh, uint8_t* __restrict__ hbuf,
       unsigned* __restrict__ flags)
{
  __shared__ __align__(16) uint8_t smem[163840];   // oversized on purpose: 1 block/CU
  const int tid  = threadIdx.x;
  const int l    = tid & 63;
  const int w    = tid >> 6;        // wave = gate index
  const int bid  = blockIdx.x;
  const int jb   = bid & 15;
  const int mg   = (bid >> 4) & 7;
  const int lstm = bid >> 7;
  const int grp  = bid >> 4;        // 0..15, 16 blocks each (lstm, mg)
  const int m0   = mg * 32;
  const int j0   = jb * 32;

  const size_t hslot = (size_t)NBAT * HIDD * 2;   // 262144 B
  const int em   = tid >> 3;        // epilogue batch row 0..31
  const int ecol = tid & 7;         // epilogue col group (4 cols)
  const int an   = l & 31;          // MFMA A-row / B-col (lane&31)
  const int ah   = l >> 5;          // k-half (lane>>5)

  // ---- load this lane's invariant W_hh B-fragments into registers ----
  // B-fragment for k-slice ks: 16B of W_hh row (w*512 + j0 + an), chunk 2ks+ah.
  bf16x8 wreg[32];
  {
    const uint8_t* wrow = whh + (size_t)(w * 512 + j0 + an) * 1024 + (size_t)ah * 16;
    #pragma unroll
    for (int ks = 0; ks < 32; ++ks)
      wreg[ks] = *(const bf16x8*)(wrow + ks * 32);
  }

  // poll address: lane i watches peer (grp*16 + (i&15))'s flag (256B stride)
  const unsigned* fpoll = flags + (size_t)(grp * 16 + (l & 15)) * 64;
  unsigned* fmine = flags + (size_t)bid * 64;

  float cst[4] = {0.f, 0.f, 0.f, 0.f};
  int tok_next = tokT[(lstm * TSEQ + 0) * NBAT + m0 + em];

  for (int t = 0; t < TSEQ; ++t) {
    const int tok_cur = tok_next;

    // ---- issue xg gather + next-token load FIRST (hides under the poll) ----
    const uint8_t* xsrc = P2 + (size_t)tok_cur * 4096 + (size_t)j0 * 8 + (size_t)ecol * 32;
    const uint4 xq0 = *(const uint4*)(xsrc);
    const uint4 xq1 = *(const uint4*)(xsrc + 16);
    if (t + 1 < TSEQ) tok_next = tokT[(lstm * TSEQ + (t + 1)) * NBAT + m0 + em];

    // ---- wait for all 16 peer blocks to have completed step t-1 ----
    if (t > 0 && w == 0) {
      const unsigned tgt = (unsigned)t;
      int guard = 0;
      for (;;) {
        const unsigned v = __hip_atomic_load(fpoll, __ATOMIC_RELAXED, __HIP_MEMORY_SCOPE_AGENT);
        if (__all((int)(v >= tgt))) break;
        __builtin_amdgcn_s_sleep(1);
        if (++guard > 400000) break;           // fail visible, not hung
      }
    }
    __syncthreads();   // B1: all waves past poll; peers' h visible

    // ---- stage h tile (32 rows x 1KB) via agent-scope atomic loads ----
    {
      const uint8_t* hb = hbuf + (size_t)(lstm * 2 + (t & 1)) * hslot
                        + (size_t)m0 * 1024 + (size_t)tid * 8;
      u64 v[16];
      #pragma unroll
      for (int i = 0; i < 16; ++i)
        v[i] = __hip_atomic_load((const u64*)(hb + (size_t)i * 2048),
                                 __ATOMIC_RELAXED, __HIP_MEMORY_SCOPE_AGENT);
      #pragma unroll
      for (int i = 0; i < 16; ++i) {
        const int m = i * 2 + (tid >> 7);
        const int c = (tid >> 1) & 63;
        const int half = tid & 1;
        *(u64*)(smem + (size_t)m * 1024 + ((c ^ (m & 7)) * 16) + half * 8) = v[i];
      }
    }
    __syncthreads();   // B2: h LDS ready

    // ---- GEMM: gate_w[32x32] = h[32x512] . W_g[32x512]^T (32x32x16 MFMA) ----
    // A from LDS, B from registers (wreg, static indices via full unroll).
    f32x16 acc0{}, acc1{};
    #pragma unroll
    for (int ks = 0; ks < 32; ++ks) {
      const int ch = ks * 2 + ah;
      const bf16x8 av = *(const bf16x8*)(smem + (size_t)an * 1024 + ((ch ^ (an & 7)) * 16));
      if (ks & 1) acc1 = __builtin_amdgcn_mfma_f32_32x32x16_bf16(av, wreg[ks], acc1, 0, 0, 0);
      else        acc0 = __builtin_amdgcn_mfma_f32_32x32x16_bf16(av, wreg[ks], acc0, 0, 0, 0);
    }
    // gate writes go to GB region (disjoint from A) -> no barrier needed here

    {
      float* gb = (float*)(smem + GB);   // gbuf[g][row 0..31][col 0..31] f32
      #pragma unroll
      for (int r = 0; r < 16; ++r) {
        const int row = (r & 3) + 8 * (r >> 2) + 4 * ah;   // 32x32 C/D mapping
        gb[w * 1024 + row * 32 + an] = acc0[r] + acc1[r];
      }
    }
    __syncthreads();   // B3: gate buffer ready

    // ---- epilogue: 4 cells/lane, lane-local nonlinearity, h -> coherence pt ----
    {
      const float* gb = (const float*)(smem + GB);
      const f32x4 pi = *(const f32x4*)(gb + 0 * 1024 + em * 32 + ecol * 4);
      const f32x4 pf = *(const f32x4*)(gb + 1 * 1024 + em * 32 + ecol * 4);
      const f32x4 pg = *(const f32x4*)(gb + 2 * 1024 + em * 32 + ecol * 4);
      const f32x4 po = *(const f32x4*)(gb + 3 * 1024 + em * 32 + ecol * 4);
      unsigned short xsv[16];
      *(uint4*)(xsv) = xq0;
      *(uint4*)(xsv + 8) = xq1;
      unsigned short hv[4];
      #pragma unroll
      for (int k = 0; k < 4; ++k) {
        const float iv = sigf(pi[k] + b2f(xsv[k * 4 + 0]));
        const float fv = sigf(pf[k] + b2f(xsv[k * 4 + 1]));
        const float gv = tanhf_(pg[k] + b2f(xsv[k * 4 + 2]));
        const float ov = sigf(po[k] + b2f(xsv[k * 4 + 3]));
        const float cv = fv * cst[k] + iv * gv;
        cst[k] = cv;
        hv[k] = f2bf(ov * tanhf_(cv));
      }
      const u64 hp = (u64)hv[0] | ((u64)hv[1] << 16) | ((u64)hv[2] << 32) | ((u64)hv[3] << 48);
      uint8_t* hdst = hbuf + (size_t)(lstm * 2 + ((t + 1) & 1)) * hslot
                    + (size_t)(m0 + em) * 1024 + (size_t)(j0 + ecol * 4) * 2;
      __hip_atomic_store((u64*)hdst, hp,
                         __ATOMIC_RELAXED, __HIP_MEMORY_SCOPE_AGENT);
    }
    __syncthreads();   // B4: barrier drain (s_waitcnt vmcnt(0)) => h at coherence pt

    if (tid == 0 && t + 1 < TSEQ)
      __hip_atomic_store(fmine, (unsigned)(t + 1),
                         __ATOMIC_RELAXED, __HIP_MEMORY_SCOPE_AGENT);
  }
}

// ------------------------------------------------------------------
// K4: h1*h2 -> logits -> softmax. one wave per batch row.
// ------------------------------------------------------------------
__global__ __launch_bounds__(64) void
k_fc(const uint8_t* __restrict__ hbuf, const float* __restrict__ wfc,
     const float* __restrict__ bfc, float* __restrict__ out)
{
  const int n = blockIdx.x, l = threadIdx.x;
  const unsigned short* h1 = (const unsigned short*)(hbuf) + (size_t)n * HIDD;
  const unsigned short* h2 = (const unsigned short*)(hbuf + 2 * (size_t)NBAT * HIDD * 2) + (size_t)n * HIDD;
  float s0 = 0.f, s1 = 0.f;
  for (int j = l; j < HIDD; j += 64) {
    float hv = b2f(h1[j]) * b2f(h2[j]);
    s0 += hv * wfc[j];
    s1 += hv * wfc[HIDD + j];
  }
  #pragma unroll
  for (int off = 32; off > 0; off >>= 1) {
    s0 += __shfl_down(s0, off, 64);
    s1 += __shfl_down(s1, off, 64);
  }
  if (l == 0) {
    s0 += bfc[0]; s1 += bfc[1];
    float m  = fmaxf(s0, s1);
    float e0 = __builtin_amdgcn_exp2f((s0 - m) * 1.4426950408889634f);
    float e1 = __builtin_amdgcn_exp2f((s1 - m) * 1.4426950408889634f);
    float inv = 1.0f / (e0 + e1);
    out[n * 2 + 0] = e0 * inv;
    out[n * 2 + 1] = e1 * inv;
  }
}

// ------------------------------------------------------------------
extern "C" void kernel_launch(void* const* d_in, const int* in_sizes, int n_in,
                              void* d_out, int out_size, void* d_ws, size_t ws_size,
                              hipStream_t stream) {
  (void)in_sizes; (void)n_in; (void)out_size;
  if (ws_size < WS_NEED) return;   // fail visibly rather than scribble OOB

  const int*   tok1 = (const int*)d_in[0];
  const int*   tok2 = (const int*)d_in[1];
  const float* emb  = (const float*)d_in[2];
  const float* wih  = (const float*)d_in[3];
  const float* whh  = (const float*)d_in[4];
  const float* bih  = (const float*)d_in[5];
  const float* bhh  = (const float*)d_in[6];
  const float* wfc  = (const float*)d_in[7];
  const float* bfc  = (const float*)d_in[8];
  float* out = (float*)d_out;

  uint8_t* ws = (uint8_t*)d_ws;
  unsigned short* P2    = (unsigned short*)(ws + O_P2);
  unsigned short* embT  = (unsigned short*)(ws + O_EMBT);
  unsigned short* wihb  = (unsigned short*)(ws + O_WIH);
  unsigned short* whhb  = (unsigned short*)(ws + O_WHH);
  int*            tokT  = (int*)(ws + O_TOKT);
  uint8_t*        hbuf  = ws + O_HBUF;
  unsigned*       flags = (unsigned*)(ws + O_FLAGS);

  k_prep<<<1024, 256, 0, stream>>>(emb, wih, whh, tok1, tok2, embT, wihb, whhb,
                                   tokT, (unsigned*)hbuf);
  k_proj<<<dim3(16, 391), 256, 0, stream>>>(embT, wihb, bih, bhh, P2);
  k_zero<<<64, 256, 0, stream>>>(flags);   // embT dead after k_proj; flags live there

  {
    const uint8_t* p2p = (const uint8_t*)P2;
    const int*     tkp = tokT;
    const uint8_t* whp = (const uint8_t*)whhb;
    uint8_t*       hbp = hbuf;
    unsigned*      flp = flags;
    void* args[5] = {(void*)&p2p, (void*)&tkp, (void*)&whp, (void*)&hbp, (void*)&flp};
    hipError_t e = hipLaunchCooperativeKernel((void*)k_lstm, dim3(256), dim3(256),
                                              args, 0, stream);
    if (e != hipSuccess) {
      (void)hipGetLastError();  // clear; fall back (256 blocks @ 1/CU are co-resident)
      k_lstm<<<256, 256, 0, stream>>>(p2p, tkp, whp, hbp, flp);
    }
  }

  k_fc<<<256, 64, 0, stream>>>(hbuf, wfc, bfc, out);
}

// Round 8
// 1953.345 us; speedup vs baseline: 1.4321x; 1.0042x over previous
//
#include <hip/hip_runtime.h>
#include <stdint.h>

// Problem constants
#define VOCAB  50000
#define EMBD   256
#define HIDD   512
#define G4     2048   // 4*HID
#define NBAT   256
#define TSEQ   512

// ---- workspace layout (bytes) ----
#define O_P2    0ull            // P2[v][j*4+g] bf16 : VOCAB*G4*2      = 204,800,000
#define O_EMBT  204800000ull    // emb bf16 [V][E] (dead after k_proj; flags live here)
#define O_WIH   230400000ull    // W_ih bf16 [G4][E]
#define O_WHH   231448576ull    // W_hh bf16 [G4][H]
#define O_TOKT  233545728ull    // tokT int [2][T][N]
#define O_HBUF  234594304ull    // h bf16 [2 lstm][2 phase][N][H] = 1 MiB
#define WS_NEED 235643136ull
#define O_FLAGS O_EMBT          // 256 flags x 256B stride = 64 KB, zeroed post-k_proj

typedef __bf16 bf16x8 __attribute__((ext_vector_type(8)));
typedef float  f32x4  __attribute__((ext_vector_type(4)));
typedef float  f32x16 __attribute__((ext_vector_type(16)));
typedef unsigned long long u64;

__device__ __forceinline__ unsigned short f2bf(float x) {
  unsigned u = __float_as_uint(x);
  u = (u + 0x7fffu + ((u >> 16) & 1u)) >> 16;   // RNE
  return (unsigned short)u;
}
__device__ __forceinline__ ushort4 f2bf4(float4 v) {
  ushort4 r; r.x = f2bf(v.x); r.y = f2bf(v.y); r.z = f2bf(v.z); r.w = f2bf(v.w);
  return r;
}
__device__ __forceinline__ float b2f(unsigned short b) {
  return __uint_as_float(((unsigned)b) << 16);
}
__device__ __forceinline__ float sigf(float x) {
  float e = __builtin_amdgcn_exp2f(-1.4426950408889634f * x);
  return __builtin_amdgcn_rcpf(1.0f + e);
}
__device__ __forceinline__ float tanhf_(float x) {
  float e = __builtin_amdgcn_exp2f(-2.8853900817779268f * x);
  return 2.0f * __builtin_amdgcn_rcpf(1.0f + e) - 1.0f;
}

// ------------------------------------------------------------------
// K1: prep — bf16 converts (float4 -> ushort4 vectorized, G13),
// token transpose, zero h (uint4)
// ------------------------------------------------------------------
__global__ void k_prep(const float* __restrict__ emb, const float* __restrict__ wih,
                       const float* __restrict__ whh, const int* __restrict__ tok1,
                       const int* __restrict__ tok2, unsigned short* __restrict__ embT,
                       unsigned short* __restrict__ wihb, unsigned short* __restrict__ whhb,
                       int* __restrict__ tokT, unsigned* __restrict__ hz)
{
  const int stride = gridDim.x * blockDim.x;
  const int id0 = blockIdx.x * blockDim.x + threadIdx.x;

  const float4* e4 = (const float4*)emb;   ushort4* eo = (ushort4*)embT;
  for (int i = id0; i < VOCAB * EMBD / 4; i += stride) eo[i] = f2bf4(e4[i]);

  const float4* i4 = (const float4*)wih;   ushort4* io = (ushort4*)wihb;
  for (int i = id0; i < G4 * EMBD / 4; i += stride)    io[i] = f2bf4(i4[i]);

  const float4* h4 = (const float4*)whh;   ushort4* ho = (ushort4*)whhb;
  for (int i = id0; i < G4 * HIDD / 4; i += stride)    ho[i] = f2bf4(h4[i]);

  for (int i = id0; i < 2 * TSEQ * NBAT; i += stride) {
    int l = i >> 17, t = (i >> 8) & 511, n = i & 255;
    tokT[i] = (l ? tok2 : tok1)[n * TSEQ + t];
  }

  uint4* hz4 = (uint4*)hz;
  const uint4 z = {0u, 0u, 0u, 0u};
  for (int i = id0; i < 65536; i += stride) hz4[i] = z;   // zero h buffers (1 MiB)
}

// ------------------------------------------------------------------
// K1b: zero progress flags (runs after k_proj; flags overlap embT region)
// ------------------------------------------------------------------
__global__ void k_zero(unsigned* __restrict__ flags)
{
  const int i = blockIdx.x * blockDim.x + threadIdx.x;
  if (i < 16384) flags[i] = 0u;   // 64 KB
}

// ------------------------------------------------------------------
// K2: vocab projection  P2[v][j*4+g] = emb[v]·W_ih[g*512+j] + b_ih + b_hh
// (unchanged — correctness-verified)
// ------------------------------------------------------------------
__global__ __launch_bounds__(256) void
k_proj(const unsigned short* __restrict__ embT, const unsigned short* __restrict__ wihb,
       const float* __restrict__ bih, const float* __restrict__ bhh,
       unsigned short* __restrict__ P2)
{
  const int l  = threadIdx.x & 63;
  const int w  = threadIdx.x >> 6;
  const int n0 = blockIdx.x * 128 + (w & 1) * 64;
  const int m0 = blockIdx.y * 128 + (w >> 1) * 64;
  const int lq = l >> 4, lc = l & 15;

  f32x4 acc[4][4];
  #pragma unroll
  for (int a = 0; a < 4; ++a)
    #pragma unroll
    for (int b = 0; b < 4; ++b) acc[a][b] = (f32x4){0.f, 0.f, 0.f, 0.f};

  const uint8_t* eb = (const uint8_t*)embT;
  const uint8_t* wb = (const uint8_t*)wihb;
  #pragma unroll
  for (int ks = 0; ks < 8; ++ks) {
    const int koff = ks * 64 + lq * 16;
    bf16x8 a[4], b[4];
    #pragma unroll
    for (int mt = 0; mt < 4; ++mt) {
      int row = m0 + mt * 16 + lc; if (row >= VOCAB) row = VOCAB - 1;
      a[mt] = *(const bf16x8*)(eb + (size_t)row * 512 + koff);
    }
    #pragma unroll
    for (int nt = 0; nt < 4; ++nt) {
      int g = n0 + nt * 16 + lc;
      b[nt] = *(const bf16x8*)(wb + (size_t)g * 512 + koff);
    }
    #pragma unroll
    for (int mt = 0; mt < 4; ++mt)
      #pragma unroll
      for (int nt = 0; nt < 4; ++nt)
        acc[mt][nt] = __builtin_amdgcn_mfma_f32_16x16x32_bf16(a[mt], b[nt], acc[mt][nt], 0, 0, 0);
  }

  #pragma unroll
  for (int mt = 0; mt < 4; ++mt)
    #pragma unroll
    for (int r = 0; r < 4; ++r) {
      const int vrow = m0 + mt * 16 + lq * 4 + r;
      if (vrow < VOCAB) {
        #pragma unroll
        for (int nt = 0; nt < 4; ++nt) {
          const int gcol = n0 + nt * 16 + lc;
          float v = acc[mt][nt][r] + bih[gcol] + bhh[gcol];
          const int colp = ((gcol & 511) << 2) | (gcol >> 9);  // [j][g] permuted
          P2[(size_t)vrow * 2048 + colp] = f2bf(v);
        }
      }
    }
}

// ------------------------------------------------------------------
// K3: persistent LSTM scan. 256 blocks x 256 threads (4 waves).
// block = (lstm, mg: 32 batch rows, jb: 32 hidden cols). wave = gate.
// Sync: agent-scope (MALL) h/flag exchange — proven baseline protocol.
// W_hh B-fragments live in 128 VGPRs/lane (loaded once, statically
// indexed via full unroll) instead of LDS:
//   - GEMM LDS traffic per step halves (256 -> 128 KB)
//   - A-tile (32KB @ 0) and gate buffer (16KB @ 32768) are disjoint
// Empirical notes (R4-R7): protocol refactors all regress —
//   R4 fused data+flag packets: MALL traffic amplification (+834us)
//   R5 per-wave flags / all-wave poll: 4x poll transactions (+225us)
//   R6 last-wave flag + asm sc0sc1 staging: +210us
//   R7 re-anchor: this config reproduces 1671us k_lstm.
// Keep: w0-only 16-line poll, agent-atomic staging, 4 barriers.
// Structural limit: ~3 serial MALL RTs/step (drain -> flag visible ->
// poll detect -> h load) ~= 7.8k cy/step. BYTE-IDENTICAL to R7.
// LDS declared 160KB to FORCE 1 block/CU.
// ------------------------------------------------------------------
#define GB 32768    // LDS offset of f32 gate buffer (A-tile occupies [0,32768))

__global__ __launch_bounds__(256, 1) void
k_lstm(const uint8_t* __restrict__ P2, const int* __restrict__ tokT,
       const uint8_t* __restrict__ whh, uint8_t* __restrict__ hbuf,
       unsigned* __restrict__ flags)
{
  __shared__ __align__(16) uint8_t smem[163840];   // oversized on purpose: 1 block/CU
  const int tid  = threadIdx.x;
  const int l    = tid & 63;
  const int w    = tid >> 6;        // wave = gate index
  const int bid  = blockIdx.x;
  const int jb   = bid & 15;
  const int mg   = (bid >> 4) & 7;
  const int lstm = bid >> 7;
  const int grp  = bid >> 4;        // 0..15, 16 blocks each (lstm, mg)
  const int m0   = mg * 32;
  const int j0   = jb * 32;

  const size_t hslot = (size_t)NBAT * HIDD * 2;   // 262144 B
  const int em   = tid >> 3;        // epilogue batch row 0..31
  const int ecol = tid & 7;         // epilogue col group (4 cols)
  const int an   = l & 31;          // MFMA A-row / B-col (lane&31)
  const int ah   = l >> 5;          // k-half (lane>>5)

  // ---- load this lane's invariant W_hh B-fragments into registers ----
  // B-fragment for k-slice ks: 16B of W_hh row (w*512 + j0 + an), chunk 2ks+ah.
  bf16x8 wreg[32];
  {
    const uint8_t* wrow = whh + (size_t)(w * 512 + j0 + an) * 1024 + (size_t)ah * 16;
    #pragma unroll
    for (int ks = 0; ks < 32; ++ks)
      wreg[ks] = *(const bf16x8*)(wrow + ks * 32);
  }

  // poll address: lane i watches peer (grp*16 + (i&15))'s flag (256B stride)
  const unsigned* fpoll = flags + (size_t)(grp * 16 + (l & 15)) * 64;
  unsigned* fmine = flags + (size_t)bid * 64;

  float cst[4] = {0.f, 0.f, 0.f, 0.f};
  int tok_next = tokT[(lstm * TSEQ + 0) * NBAT + m0 + em];

  for (int t = 0; t < TSEQ; ++t) {
    const int tok_cur = tok_next;

    // ---- issue xg gather + next-token load FIRST (hides under the poll) ----
    const uint8_t* xsrc = P2 + (size_t)tok_cur * 4096 + (size_t)j0 * 8 + (size_t)ecol * 32;
    const uint4 xq0 = *(const uint4*)(xsrc);
    const uint4 xq1 = *(const uint4*)(xsrc + 16);
    if (t + 1 < TSEQ) tok_next = tokT[(lstm * TSEQ + (t + 1)) * NBAT + m0 + em];

    // ---- wait for all 16 peer blocks to have completed step t-1 ----
    if (t > 0 && w == 0) {
      const unsigned tgt = (unsigned)t;
      int guard = 0;
      for (;;) {
        const unsigned v = __hip_atomic_load(fpoll, __ATOMIC_RELAXED, __HIP_MEMORY_SCOPE_AGENT);
        if (__all((int)(v >= tgt))) break;
        __builtin_amdgcn_s_sleep(1);
        if (++guard > 400000) break;           // fail visible, not hung
      }
    }
    __syncthreads();   // B1: all waves past poll; peers' h visible

    // ---- stage h tile (32 rows x 1KB) via agent-scope atomic loads ----
    {
      const uint8_t* hb = hbuf + (size_t)(lstm * 2 + (t & 1)) * hslot
                        + (size_t)m0 * 1024 + (size_t)tid * 8;
      u64 v[16];
      #pragma unroll
      for (int i = 0; i < 16; ++i)
        v[i] = __hip_atomic_load((const u64*)(hb + (size_t)i * 2048),
                                 __ATOMIC_RELAXED, __HIP_MEMORY_SCOPE_AGENT);
      #pragma unroll
      for (int i = 0; i < 16; ++i) {
        const int m = i * 2 + (tid >> 7);
        const int c = (tid >> 1) & 63;
        const int half = tid & 1;
        *(u64*)(smem + (size_t)m * 1024 + ((c ^ (m & 7)) * 16) + half * 8) = v[i];
      }
    }
    __syncthreads();   // B2: h LDS ready

    // ---- GEMM: gate_w[32x32] = h[32x512] . W_g[32x512]^T (32x32x16 MFMA) ----
    // A from LDS, B from registers (wreg, static indices via full unroll).
    f32x16 acc0{}, acc1{};
    #pragma unroll
    for (int ks = 0; ks < 32; ++ks) {
      const int ch = ks * 2 + ah;
      const bf16x8 av = *(const bf16x8*)(smem + (size_t)an * 1024 + ((ch ^ (an & 7)) * 16));
      if (ks & 1) acc1 = __builtin_amdgcn_mfma_f32_32x32x16_bf16(av, wreg[ks], acc1, 0, 0, 0);
      else        acc0 = __builtin_amdgcn_mfma_f32_32x32x16_bf16(av, wreg[ks], acc0, 0, 0, 0);
    }
    // gate writes go to GB region (disjoint from A) -> no barrier needed here

    {
      float* gb = (float*)(smem + GB);   // gbuf[g][row 0..31][col 0..31] f32
      #pragma unroll
      for (int r = 0; r < 16; ++r) {
        const int row = (r & 3) + 8 * (r >> 2) + 4 * ah;   // 32x32 C/D mapping
        gb[w * 1024 + row * 32 + an] = acc0[r] + acc1[r];
      }
    }
    __syncthreads();   // B3: gate buffer ready

    // ---- epilogue: 4 cells/lane, lane-local nonlinearity, h -> coherence pt ----
    {
      const float* gb = (const float*)(smem + GB);
      const f32x4 pi = *(const f32x4*)(gb + 0 * 1024 + em * 32 + ecol * 4);
      const f32x4 pf = *(const f32x4*)(gb + 1 * 1024 + em * 32 + ecol * 4);
      const f32x4 pg = *(const f32x4*)(gb + 2 * 1024 + em * 32 + ecol * 4);
      const f32x4 po = *(const f32x4*)(gb + 3 * 1024 + em * 32 + ecol * 4);
      unsigned short xsv[16];
      *(uint4*)(xsv) = xq0;
      *(uint4*)(xsv + 8) = xq1;
      unsigned short hv[4];
      #pragma unroll
      for (int k = 0; k < 4; ++k) {
        const float iv = sigf(pi[k] + b2f(xsv[k * 4 + 0]));
        const float fv = sigf(pf[k] + b2f(xsv[k * 4 + 1]));
        const float gv = tanhf_(pg[k] + b2f(xsv[k * 4 + 2]));
        const float ov = sigf(po[k] + b2f(xsv[k * 4 + 3]));
        const float cv = fv * cst[k] + iv * gv;
        cst[k] = cv;
        hv[k] = f2bf(ov * tanhf_(cv));
      }
      const u64 hp = (u64)hv[0] | ((u64)hv[1] << 16) | ((u64)hv[2] << 32) | ((u64)hv[3] << 48);
      uint8_t* hdst = hbuf + (size_t)(lstm * 2 + ((t + 1) & 1)) * hslot
                    + (size_t)(m0 + em) * 1024 + (size_t)(j0 + ecol * 4) * 2;
      __hip_atomic_store((u64*)hdst, hp,
                         __ATOMIC_RELAXED, __HIP_MEMORY_SCOPE_AGENT);
    }
    __syncthreads();   // B4: barrier drain (s_waitcnt vmcnt(0)) => h at coherence pt

    if (tid == 0 && t + 1 < TSEQ)
      __hip_atomic_store(fmine, (unsigned)(t + 1),
                         __ATOMIC_RELAXED, __HIP_MEMORY_SCOPE_AGENT);
  }
}

// ------------------------------------------------------------------
// K4: h1*h2 -> logits -> softmax. one wave per batch row.
// u64 (4x bf16) h loads + float4 W_fc loads (G13).
// ------------------------------------------------------------------
__global__ __launch_bounds__(64) void
k_fc(const uint8_t* __restrict__ hbuf, const float* __restrict__ wfc,
     const float* __restrict__ bfc, float* __restrict__ out)
{
  const int n = blockIdx.x, l = threadIdx.x;
  const u64* h1 = (const u64*)(hbuf + (size_t)n * 1024);
  const u64* h2 = (const u64*)(hbuf + 2 * (size_t)NBAT * HIDD * 2 + (size_t)n * 1024);
  const float4* w0 = (const float4*)wfc;           // 128 float4 per row
  const float4* w1 = (const float4*)(wfc + HIDD);
  float s0 = 0.f, s1 = 0.f;
  for (int p = l; p < 128; p += 64) {
    const u64 k1 = h1[p], k2 = h2[p];
    const float4 a = w0[p], b = w1[p];
    const float hv0 = b2f((unsigned short)k1)         * b2f((unsigned short)k2);
    const float hv1 = b2f((unsigned short)(k1 >> 16)) * b2f((unsigned short)(k2 >> 16));
    const float hv2 = b2f((unsigned short)(k1 >> 32)) * b2f((unsigned short)(k2 >> 32));
    const float hv3 = b2f((unsigned short)(k1 >> 48)) * b2f((unsigned short)(k2 >> 48));
    s0 += hv0 * a.x + hv1 * a.y + hv2 * a.z + hv3 * a.w;
    s1 += hv0 * b.x + hv1 * b.y + hv2 * b.z + hv3 * b.w;
  }
  #pragma unroll
  for (int off = 32; off > 0; off >>= 1) {
    s0 += __shfl_down(s0, off, 64);
    s1 += __shfl_down(s1, off, 64);
  }
  if (l == 0) {
    s0 += bfc[0]; s1 += bfc[1];
    float m  = fmaxf(s0, s1);
    float e0 = __builtin_amdgcn_exp2f((s0 - m) * 1.4426950408889634f);
    float e1 = __builtin_amdgcn_exp2f((s1 - m) * 1.4426950408889634f);
    float inv = 1.0f / (e0 + e1);
    out[n * 2 + 0] = e0 * inv;
    out[n * 2 + 1] = e1 * inv;
  }
}

// ------------------------------------------------------------------
extern "C" void kernel_launch(void* const* d_in, const int* in_sizes, int n_in,
                              void* d_out, int out_size, void* d_ws, size_t ws_size,
                              hipStream_t stream) {
  (void)in_sizes; (void)n_in; (void)out_size;
  if (ws_size < WS_NEED) return;   // fail visibly rather than scribble OOB

  const int*   tok1 = (const int*)d_in[0];
  const int*   tok2 = (const int*)d_in[1];
  const float* emb  = (const float*)d_in[2];
  const float* wih  = (const float*)d_in[3];
  const float* whh  = (const float*)d_in[4];
  const float* bih  = (const float*)d_in[5];
  const float* bhh  = (const float*)d_in[6];
  const float* wfc  = (const float*)d_in[7];
  const float* bfc  = (const float*)d_in[8];
  float* out = (float*)d_out;

  uint8_t* ws = (uint8_t*)d_ws;
  unsigned short* P2    = (unsigned short*)(ws + O_P2);
  unsigned short* embT  = (unsigned short*)(ws + O_EMBT);
  unsigned short* wihb  = (unsigned short*)(ws + O_WIH);
  unsigned short* whhb  = (unsigned short*)(ws + O_WHH);
  int*            tokT  = (int*)(ws + O_TOKT);
  uint8_t*        hbuf  = ws + O_HBUF;
  unsigned*       flags = (unsigned*)(ws + O_FLAGS);

  k_prep<<<1024, 256, 0, stream>>>(emb, wih, whh, tok1, tok2, embT, wihb, whhb,
                                   tokT, (unsigned*)hbuf);
  k_proj<<<dim3(16, 391), 256, 0, stream>>>(embT, wihb, bih, bhh, P2);
  k_zero<<<64, 256, 0, stream>>>(flags);   // embT dead after k_proj; flags live there

  {
    const uint8_t* p2p = (const uint8_t*)P2;
    const int*     tkp = tokT;
    const uint8_t* whp = (const uint8_t*)whhb;
    uint8_t*       hbp = hbuf;
    unsigned*      flp = flags;
    void* args[5] = {(void*)&p2p, (void*)&tkp, (void*)&whp, (void*)&hbp, (void*)&flp};
    hipError_t e = hipLaunchCooperativeKernel((void*)k_lstm, dim3(256), dim3(256),
                                              args, 0, stream);
    if (e != hipSuccess) {
      (void)hipGetLastError();  // clear; fall back (256 blocks @ 1/CU are co-resident)
      k_lstm<<<256, 256, 0, stream>>>(p2p, tkp, whp, hbp, flp);
    }
  }

  k_fc<<<256, 64, 0, stream>>>(hbuf, wfc, bfc, out);
}